// Round 12
// baseline (549.995 us; speedup 1.0000x reference)
//
#include <hip/hip_runtime.h>
#include <hip/hip_bf16.h>
#include <cstdint>
#include <cstddef>

#define NATOMS 8192
#define DIM 32
#define NSEQ 4096
#define KSPLIT 16
#define BM 256
#define BK 32
#define KPB (NATOMS / KSPLIT)   // 512 k per block
#define NT (KPB / BK)           // 16 tiles
#define NBLK 512

typedef __attribute__((address_space(1))) const void GV;
typedef __attribute__((address_space(3))) void LV;
using bf16x8 = __attribute__((ext_vector_type(8))) short;
using f32x4  = __attribute__((ext_vector_type(4))) float;
using u32x2  = __attribute__((ext_vector_type(2))) unsigned int;

__device__ __forceinline__ void async16(void* lds, const void* g) {
  __builtin_amdgcn_global_load_lds((GV*)g, (LV*)lds, 16, 0, 0);
}
__device__ __forceinline__ void async16nt(void* lds, const void* g) {
  __builtin_amdgcn_global_load_lds((GV*)g, (LV*)lds, 16, 0, 2);
}
__device__ __forceinline__ uint32_t pkbf(float lo, float hi) {
  union { __hip_bfloat16 b[2]; uint32_t u; } v;
  v.b[0] = __float2bfloat16(lo);
  v.b[1] = __float2bfloat16(hi);
  return v.u;
}
__device__ __forceinline__ float ubf(ushort u) {
  union { ushort u; __hip_bfloat16 b; } v;
  v.u = u;
  return __bfloat162float(v.b);
}
__device__ __forceinline__ ushort bfr(float a) {
  union { __hip_bfloat16 b; ushort u; } v;
  v.b = __float2bfloat16(a);
  return v.u;
}
union U8 { uint32_t u[4]; bf16x8 v; };

__device__ __forceinline__ int aslot(int r, int g) { return g ^ ((r >> 1) & 3); }
__device__ __forceinline__ int hslot(int n, int g) { return g ^ ((n >> 1) & 3); }

// Sense-reversing grid barrier. count self-resets to 0 each use; gen toggles
// (any initial value works). Release/acquire on agent scope gives cross-XCD
// visibility of all prior stores (validated in round 11).
__device__ __forceinline__ void gridbar(int* cnt, int* gen, int tid) {
  __syncthreads();  // drains each wave's vmcnt before tid0 publishes
  if (tid == 0) {
    int g = __hip_atomic_load(gen, __ATOMIC_RELAXED, __HIP_MEMORY_SCOPE_AGENT);
    if (__hip_atomic_fetch_add(cnt, 1, __ATOMIC_ACQ_REL,
                               __HIP_MEMORY_SCOPE_AGENT) == NBLK - 1) {
      __hip_atomic_store(cnt, 0, __ATOMIC_RELAXED, __HIP_MEMORY_SCOPE_AGENT);
      __hip_atomic_store(gen, g ^ 1, __ATOMIC_RELEASE,
                         __HIP_MEMORY_SCOPE_AGENT);
    } else {
      while (__hip_atomic_load(gen, __ATOMIC_ACQUIRE,
                               __HIP_MEMORY_SCOPE_AGENT) == g)
        __builtin_amdgcn_s_sleep(8);
    }
  }
  __syncthreads();
}

// ---------------------------------------------------------------------------
// gemm2 body (round-9 proven): Pb(bf16) = Abf @ hTin, 3-deep counted pipeline
// ---------------------------------------------------------------------------
__device__ __forceinline__ void gemm2_body(
    const ushort* __restrict__ Abf, const ushort* __restrict__ hTin,
    ushort* __restrict__ Pb, int ntA, ushort* AbB, ushort* HbU, int tid,
    int wave, int lane, int l15, int l4, int rb, int ks, int k0) {
  f32x4 acc[4][2];
#pragma unroll
  for (int rt = 0; rt < 4; ++rt)
#pragma unroll
    for (int ct = 0; ct < 2; ++ct) acc[rt][ct] = {0.f, 0.f, 0.f, 0.f};

  auto stage = [&](int buf, int t) {
    const ushort* Tb = Abf + (((size_t)ks * 32 + rb) * 16 + t) * (BM * BK);
#pragma unroll
    for (int i = 0; i < 4; ++i) {
      const ushort* src = Tb + ((wave * 4 + i) * 64 + lane) * 8;
      void* dst = AbB + buf * 8192 + (wave * 4 + i) * 512;
      if (ntA)
        async16nt(dst, src);
      else
        async16(dst, src);
    }
    if (wave < 2) {
      const int kb = k0 + t * BK;
      const int E = wave * 64 + lane;
      const int n = E >> 2;
      const int s = E & 3;
      const ushort* src = hTin + (size_t)n * NATOMS + kb + (hslot(n, s) << 3);
      async16(HbU + buf * 1024 + wave * 512, src);
    }
  };

  stage(0, 0);
  stage(1, 1);

#pragma unroll 1
  for (int t = 0; t < NT; ++t) {
    if (t + 1 < NT) {
      if (wave < 2)
        asm volatile("s_waitcnt vmcnt(5)" ::: "memory");
      else
        asm volatile("s_waitcnt vmcnt(4)" ::: "memory");
    } else {
      asm volatile("s_waitcnt vmcnt(0)" ::: "memory");
    }
    __syncthreads();
    if (t + 2 < NT) stage((t + 2) % 3, t + 2);

    const ushort* Ac = AbB + (t % 3) * 8192;
    const ushort* Hc = HbU + (t % 3) * 1024;

    bf16x8 av[4], bv[2];
#pragma unroll
    for (int rt = 0; rt < 4; ++rt) {
      const int r = wave * 64 + rt * 16 + l15;
      av[rt] = *(const bf16x8*)(Ac + r * 32 + (aslot(r, l4) << 3));
    }
#pragma unroll
    for (int ct = 0; ct < 2; ++ct) {
      const int n = ct * 16 + l15;
      bv[ct] = *(const bf16x8*)(Hc + n * 32 + (hslot(n, l4) << 3));
    }

#pragma unroll
    for (int rt = 0; rt < 4; ++rt)
#pragma unroll
      for (int ct = 0; ct < 2; ++ct)
        acc[rt][ct] = __builtin_amdgcn_mfma_f32_16x16x32_bf16(
            av[rt], bv[ct], acc[rt][ct], 0, 0, 0);
  }

  ushort* Pp = Pb + ((((size_t)ks * 32 + rb) * 4 + wave) * 8) * 256;
#pragma unroll
  for (int rt = 0; rt < 4; ++rt)
#pragma unroll
    for (int ct = 0; ct < 2; ++ct) {
      u32x2 u;
      u.x = pkbf(acc[rt][ct].x, acc[rt][ct].y);
      u.y = pkbf(acc[rt][ct].z, acc[rt][ct].w);
      *(u32x2*)(Pp + (rt * 2 + ct) * 256 + lane * 4) = u;
    }
}

// ---------------------------------------------------------------------------
// reduce body: xsr[2] += sum_ks partials (row block = 16 rows per block);
// optional h-step -> hTout. FP order identical to round 9.
// ---------------------------------------------------------------------------
__device__ __forceinline__ void reduce_body(
    const float* __restrict__ P, const ushort* __restrict__ Pb, int isbf,
    const float* __restrict__ Wn, const float* __restrict__ bn,
    ushort* __restrict__ hTout, int doH, float* xsr, float* xsl, float* Wl,
    int row0r, int tid) {
  const int col = tid & 31;
  if (doH)
    for (int i = tid; i < DIM * DIM; i += 256) Wl[i] = Wn[i];
#pragma unroll
  for (int rr = 0; rr < 2; ++rr) {
    const int lr = (tid >> 5) + rr * 8;
    const int row = row0r + lr;
    const int rbv = row >> 8, r255 = row & 255;
    const int w = r255 >> 6, rr6 = r255 & 63;
    const int rt = rr6 >> 4, q4 = (rr6 >> 2) & 3, i = rr6 & 3;
    const int ct = col >> 4, lane = q4 * 16 + (col & 15);
    const int base = ((rbv * 4 + w) * 8 + rt * 2 + ct) * 256 + lane * 4 + i;
    float s = xsr[rr];
    if (isbf) {
#pragma unroll
      for (int k = 0; k < KSPLIT; ++k)
        s += ubf(Pb[(size_t)k * (NATOMS * DIM) + base]);
    } else {
#pragma unroll
      for (int k = 0; k < KSPLIT; ++k)
        s += __builtin_nontemporal_load(&P[(size_t)k * (NATOMS * DIM) + base]);
    }
    xsr[rr] = s;
    if (doH) xsl[lr * DIM + col] = s;
  }
  if (doH) {
    __syncthreads();
    float wc[DIM];
#pragma unroll
    for (int d = 0; d < DIM; ++d) wc[d] = Wl[d * DIM + col];
    const float bb = bn[col];
#pragma unroll
    for (int rr = 0; rr < 2; ++rr) {
      const int lr = (tid >> 5) + rr * 8;
      float a = bb;
#pragma unroll
      for (int d = 0; d < DIM; ++d) a += xsl[lr * DIM + d] * wc[d];
      hTout[(size_t)col * NATOMS + row0r + lr] = bfr(fmaxf(a, 0.f));
    }
  }
}

// ---------------------------------------------------------------------------
// The persistent mega kernel: front | gemm1 | reduce | gemm2 | reduce |
// gemm3 | reduce, separated by grid barriers. 512 blocks, 2/CU resident.
// ---------------------------------------------------------------------------
__global__ __launch_bounds__(256, 2)
void cpi_mega(const int* __restrict__ fp, const float* __restrict__ adj,
              const int* __restrict__ words, const float* __restrict__ embfp,
              const float* __restrict__ embw, const float* __restrict__ Wg,
              const float* __restrict__ bg, float* __restrict__ out,
              float* __restrict__ P, ushort* __restrict__ Pb,
              ushort* __restrict__ Abf, ushort* __restrict__ hTa,
              ushort* __restrict__ hTb, int* __restrict__ bar) {
  __shared__ __align__(16) char smem[71680];  // 70 KB -> 2 blocks/CU
  float*  AbF = (float*)smem;           // gemm1: 2 x 32 KB fp32 A
  ushort* AbB = (ushort*)smem;          // gemm2: 3 x 16 KB bf16 A
  ushort* HbU = (ushort*)(smem + 65536);  // 3 x 2 KB h tiles
  float*  xsl = (float*)smem;           // reduce/front: 16 x 32 fp32
  float*  Wl  = (float*)(smem + 4096);  // 32 x 32 fp32

  const int tid   = threadIdx.x;
  const int bid   = blockIdx.x;
  const int wave  = tid >> 6;
  const int lane  = tid & 63;
  const int l15   = lane & 15;
  const int l4    = lane >> 4;
  const int rb    = bid & 31;
  const int ks    = bid >> 5;
  const int row0g = rb * BM;
  const int k0    = ks * KPB;
  const int row0r = bid * 16;
  const int col   = tid & 31;

  float xsr[2];  // this thread's 2 xs elements, live across all phases

  // ---------------- phase 0: front (words + gather + h0 -> hTa) ------------
  {
    const int wi = bid * 256 + tid;  // 512*256 = 131072 = NSEQ*DIM exactly
    out[NATOMS * DIM + wi] = embw[(size_t)words[wi >> 5] * DIM + (wi & 31)];
    for (int i = tid; i < DIM * DIM; i += 256) Wl[i] = Wg[i];
#pragma unroll
    for (int rr = 0; rr < 2; ++rr) {
      const int lr = (tid >> 5) + rr * 8;
      const float v = embfp[(size_t)fp[row0r + lr] * DIM + col];
      xsr[rr] = v;
      xsl[lr * DIM + col] = v;
    }
    __syncthreads();
    float wc[DIM];
#pragma unroll
    for (int d = 0; d < DIM; ++d) wc[d] = Wl[d * DIM + col];
    const float bb = bg[col];
#pragma unroll
    for (int rr = 0; rr < 2; ++rr) {
      const int lr = (tid >> 5) + rr * 8;
      float a = bb;
#pragma unroll
      for (int d = 0; d < DIM; ++d) a += xsl[lr * DIM + d] * wc[d];
      hTa[(size_t)col * NATOMS + row0r + lr] = bfr(fmaxf(a, 0.f));
    }
  }
  gridbar(bar, bar + 1, tid);

  // ---------------- phase 2: gemm1 (fp32 A -> bf16 MFMA + Abf image) -------
  {
    f32x4 acc[4][2];
#pragma unroll
    for (int rt = 0; rt < 4; ++rt)
#pragma unroll
      for (int ct = 0; ct < 2; ++ct) acc[rt][ct] = {0.f, 0.f, 0.f, 0.f};

    auto stage = [&](int buf, int t) {
      const int kb = k0 + t * BK;
#pragma unroll
      for (int i = 0; i < 8; ++i) {
        const int D = (wave * 8 + i) * 64 + lane;
        const int r = D >> 3;
        const int c = D & 7;
        const float* src =
            adj + (size_t)(row0g + r) * NATOMS + kb + ((c ^ (r & 7)) << 2);
        async16nt(AbF + buf * 8192 + (wave * 8 + i) * 256, src);
      }
      if (wave < 2) {
        const int E = wave * 64 + lane;
        const int n = E >> 2;
        const int s = E & 3;
        const ushort* src =
            hTa + (size_t)n * NATOMS + kb + (hslot(n, s) << 3);
        async16(HbU + buf * 1024 + wave * 512, src);
      }
    };

    stage(0, 0);
    asm volatile("s_waitcnt vmcnt(0)" ::: "memory");
    __syncthreads();

    int cur = 0;
#pragma unroll 1
    for (int t = 0; t < NT; ++t) {
      if (t + 1 < NT) stage(cur ^ 1, t + 1);

      const float*  Ac = AbF + cur * 8192;
      const ushort* Hc = HbU + cur * 1024;

      bf16x8 av[4];
#pragma unroll
      for (int rt = 0; rt < 4; ++rt) {
        const int r = wave * 64 + rt * 16 + l15;
        const float4 f0 =
            *(const float4*)(Ac + r * 32 + (((2 * l4) ^ (r & 7)) << 2));
        const float4 f1 =
            *(const float4*)(Ac + r * 32 + (((2 * l4 + 1) ^ (r & 7)) << 2));
        U8 u;
        u.u[0] = pkbf(f0.x, f0.y);
        u.u[1] = pkbf(f0.z, f0.w);
        u.u[2] = pkbf(f1.x, f1.y);
        u.u[3] = pkbf(f1.z, f1.w);
        av[rt] = u.v;
      }
      bf16x8 bv[2];
#pragma unroll
      for (int ct = 0; ct < 2; ++ct) {
        const int n = ct * 16 + l15;
        bv[ct] = *(const bf16x8*)(Hc + n * 32 + (hslot(n, l4) << 3));
      }

      ushort* Tb = Abf + (((size_t)ks * 32 + rb) * 16 + t) * (BM * BK);
#pragma unroll
      for (int rt = 0; rt < 4; ++rt) {
        const int r = wave * 64 + rt * 16 + l15;
        *(bf16x8*)(Tb + r * 32 + (aslot(r, l4) << 3)) = av[rt];
      }

#pragma unroll
      for (int rt = 0; rt < 4; ++rt)
#pragma unroll
        for (int ct = 0; ct < 2; ++ct)
          acc[rt][ct] = __builtin_amdgcn_mfma_f32_16x16x32_bf16(
              av[rt], bv[ct], acc[rt][ct], 0, 0, 0);

      asm volatile("s_waitcnt vmcnt(4)" ::: "memory");
      __syncthreads();
      cur ^= 1;
    }

    float* Pp = P + ((((size_t)ks * 32 + rb) * 4 + wave) * 8) * 256;
#pragma unroll
    for (int rt = 0; rt < 4; ++rt)
#pragma unroll
      for (int ct = 0; ct < 2; ++ct)
        *(f32x4*)(Pp + (rt * 2 + ct) * 256 + lane * 4) = acc[rt][ct];
  }
  gridbar(bar, bar + 1, tid);

  // ---------------- phase 4: reduce0 (fp32 P) + h1 -> hTb ------------------
  reduce_body(P, Pb, 0, Wg + DIM * DIM, bg + DIM, hTb, 1, xsr, xsl, Wl,
              row0r, tid);
  gridbar(bar, bar + 1, tid);

  // ---------------- phase 6: gemm2 layer 1 ---------------------------------
  gemm2_body(Abf, hTb, Pb, 0, AbB, HbU, tid, wave, lane, l15, l4, rb, ks, k0);
  gridbar(bar, bar + 1, tid);

  // ---------------- phase 8: reduce1 (bf16 Pb) + h2 -> hTa -----------------
  reduce_body(P, Pb, 1, Wg + 2 * DIM * DIM, bg + 2 * DIM, hTa, 1, xsr, xsl,
              Wl, row0r, tid);
  gridbar(bar, bar + 1, tid);

  // ---------------- phase 10: gemm3 (NT Abf reads) -------------------------
  gemm2_body(Abf, hTa, Pb, 1, AbB, HbU, tid, wave, lane, l15, l4, rb, ks, k0);
  gridbar(bar, bar + 1, tid);

  // ---------------- phase 12: reduce2 -> final xs --------------------------
  reduce_body(P, Pb, 1, Wg, bg, hTb, 0, xsr, xsl, Wl, row0r, tid);
#pragma unroll
  for (int rr = 0; rr < 2; ++rr) {
    const int lr = (tid >> 5) + rr * 8;
    out[(size_t)(row0r + lr) * DIM + col] = xsr[rr];
  }
}

extern "C" void kernel_launch(void* const* d_in, const int* in_sizes, int n_in,
                              void* d_out, int out_size, void* d_ws, size_t ws_size,
                              hipStream_t stream) {
  const int*   fp    = (const int*)d_in[0];
  const float* adj   = (const float*)d_in[1];
  const int*   words = (const int*)d_in[2];
  const float* embfp = (const float*)d_in[3];
  const float* embw  = (const float*)d_in[4];
  const float* Wg    = (const float*)d_in[5];
  const float* bg    = (const float*)d_in[6];

  float* out = (float*)d_out;

  float*  P   = (float*)d_ws;                               // 16 MB fp32 P0
  ushort* Pb  = (ushort*)P;                                 // 8 MB bf16 P1/P2
  ushort* Abf = (ushort*)(P + (size_t)KSPLIT * NATOMS * DIM);  // 128 MB bf16 A
  ushort* hTa = Abf + (size_t)NATOMS * NATOMS;              // 512 KB bf16 h^T
  ushort* hTb = hTa + (size_t)DIM * NATOMS;                 // 512 KB bf16 h^T
  int*    bar = (int*)(hTb + (size_t)DIM * NATOMS);         // {count, gen}

  hipMemsetAsync(bar, 0, 8, stream);  // count must start 0 each call
  cpi_mega<<<dim3(NBLK), dim3(256), 0, stream>>>(
      fp, adj, words, embfp, embw, Wg, bg, out, P, Pb, Abf, hTa, hTb, bar);
}

// Round 13
// 410.701 us; speedup vs baseline: 1.3392x; 1.3392x over previous
//
#include <hip/hip_runtime.h>
#include <hip/hip_bf16.h>
#include <cstdint>
#include <cstddef>

#define NATOMS 8192
#define DIM 32
#define NSEQ 4096
#define KSPLIT 16
#define BM 256
#define BK 32
#define KPB (NATOMS / KSPLIT)   // 512 k per block
#define NT (KPB / BK)           // 16 tiles
#define NBLK 512

typedef __attribute__((address_space(1))) const void GV;
typedef __attribute__((address_space(3))) void LV;
using bf16x8 = __attribute__((ext_vector_type(8))) short;
using f32x4  = __attribute__((ext_vector_type(4))) float;
using u32x2  = __attribute__((ext_vector_type(2))) unsigned int;

__device__ __forceinline__ void async16(void* lds, const void* g) {
  __builtin_amdgcn_global_load_lds((GV*)g, (LV*)lds, 16, 0, 0);
}
__device__ __forceinline__ void async16nt(void* lds, const void* g) {
  __builtin_amdgcn_global_load_lds((GV*)g, (LV*)lds, 16, 0, 2);
}
__device__ __forceinline__ uint32_t pkbf(float lo, float hi) {
  union { __hip_bfloat16 b[2]; uint32_t u; } v;
  v.b[0] = __float2bfloat16(lo);
  v.b[1] = __float2bfloat16(hi);
  return v.u;
}
__device__ __forceinline__ float ubf(ushort u) {
  union { ushort u; __hip_bfloat16 b; } v;
  v.u = u;
  return __bfloat162float(v.b);
}
__device__ __forceinline__ ushort bfr(float a) {
  union { __hip_bfloat16 b; ushort u; } v;
  v.b = __float2bfloat16(a);
  return v.u;
}
union U8 { uint32_t u[4]; bf16x8 v; };

__device__ __forceinline__ int aslot(int r, int g) { return g ^ ((r >> 1) & 3); }
__device__ __forceinline__ int hslot(int n, int g) { return g ^ ((n >> 1) & 3); }

// Sense-reversing grid barrier, invalidate-minimal form.
// - arrival: RELEASE fetch_add (writeback only; no L2 invalidate -> does not
//   disturb still-computing blocks, unlike r12's ACQ_REL+acquire-spin).
// - wait: RELAXED polls (agent-scope atomic load bypasses non-coherent
//   caches for visibility; emits NO invalidate).
// - exit: exactly ONE acquire fence per block (the semantically required
//   cross-XCD invalidate at the phase boundary).
__device__ __forceinline__ void gridbar(int* cnt, int* gen, int tid) {
  __syncthreads();  // drains vmcnt: all prior stores complete before publish
  if (tid == 0) {
    int g = __hip_atomic_load(gen, __ATOMIC_RELAXED, __HIP_MEMORY_SCOPE_AGENT);
    if (__hip_atomic_fetch_add(cnt, 1, __ATOMIC_RELEASE,
                               __HIP_MEMORY_SCOPE_AGENT) == NBLK - 1) {
      __builtin_amdgcn_fence(__ATOMIC_ACQUIRE, "agent");  // pull all stores
      __hip_atomic_store(cnt, 0, __ATOMIC_RELAXED, __HIP_MEMORY_SCOPE_AGENT);
      __hip_atomic_store(gen, g ^ 1, __ATOMIC_RELEASE,
                         __HIP_MEMORY_SCOPE_AGENT);
    } else {
      while (__hip_atomic_load(gen, __ATOMIC_RELAXED,
                               __HIP_MEMORY_SCOPE_AGENT) == g)
        __builtin_amdgcn_s_sleep(32);
      __builtin_amdgcn_fence(__ATOMIC_ACQUIRE, "agent");
    }
  }
  __syncthreads();
}

// ---------------------------------------------------------------------------
// gemm2 body (round-9 proven): Pb(bf16) = Abf @ hTin, 3-deep counted pipeline
// ---------------------------------------------------------------------------
__device__ __forceinline__ void gemm2_body(
    const ushort* __restrict__ Abf, const ushort* __restrict__ hTin,
    ushort* __restrict__ Pb, int ntA, ushort* AbB, ushort* HbU, int tid,
    int wave, int lane, int l15, int l4, int rb, int ks, int k0) {
  f32x4 acc[4][2];
#pragma unroll
  for (int rt = 0; rt < 4; ++rt)
#pragma unroll
    for (int ct = 0; ct < 2; ++ct) acc[rt][ct] = {0.f, 0.f, 0.f, 0.f};

  auto stage = [&](int buf, int t) {
    const ushort* Tb = Abf + (((size_t)ks * 32 + rb) * 16 + t) * (BM * BK);
#pragma unroll
    for (int i = 0; i < 4; ++i) {
      const ushort* src = Tb + ((wave * 4 + i) * 64 + lane) * 8;
      void* dst = AbB + buf * 8192 + (wave * 4 + i) * 512;
      if (ntA)
        async16nt(dst, src);
      else
        async16(dst, src);
    }
    if (wave < 2) {
      const int kb = k0 + t * BK;
      const int E = wave * 64 + lane;
      const int n = E >> 2;
      const int s = E & 3;
      const ushort* src = hTin + (size_t)n * NATOMS + kb + (hslot(n, s) << 3);
      async16(HbU + buf * 1024 + wave * 512, src);
    }
  };

  stage(0, 0);
  stage(1, 1);

#pragma unroll 1
  for (int t = 0; t < NT; ++t) {
    if (t + 1 < NT) {
      if (wave < 2)
        asm volatile("s_waitcnt vmcnt(5)" ::: "memory");
      else
        asm volatile("s_waitcnt vmcnt(4)" ::: "memory");
    } else {
      asm volatile("s_waitcnt vmcnt(0)" ::: "memory");
    }
    __syncthreads();
    if (t + 2 < NT) stage((t + 2) % 3, t + 2);

    const ushort* Ac = AbB + (t % 3) * 8192;
    const ushort* Hc = HbU + (t % 3) * 1024;

    bf16x8 av[4], bv[2];
#pragma unroll
    for (int rt = 0; rt < 4; ++rt) {
      const int r = wave * 64 + rt * 16 + l15;
      av[rt] = *(const bf16x8*)(Ac + r * 32 + (aslot(r, l4) << 3));
    }
#pragma unroll
    for (int ct = 0; ct < 2; ++ct) {
      const int n = ct * 16 + l15;
      bv[ct] = *(const bf16x8*)(Hc + n * 32 + (hslot(n, l4) << 3));
    }

#pragma unroll
    for (int rt = 0; rt < 4; ++rt)
#pragma unroll
      for (int ct = 0; ct < 2; ++ct)
        acc[rt][ct] = __builtin_amdgcn_mfma_f32_16x16x32_bf16(
            av[rt], bv[ct], acc[rt][ct], 0, 0, 0);
  }

  ushort* Pp = Pb + ((((size_t)ks * 32 + rb) * 4 + wave) * 8) * 256;
#pragma unroll
  for (int rt = 0; rt < 4; ++rt)
#pragma unroll
    for (int ct = 0; ct < 2; ++ct) {
      u32x2 u;
      u.x = pkbf(acc[rt][ct].x, acc[rt][ct].y);
      u.y = pkbf(acc[rt][ct].z, acc[rt][ct].w);
      *(u32x2*)(Pp + (rt * 2 + ct) * 256 + lane * 4) = u;
    }
}

// ---------------------------------------------------------------------------
// reduce body: xsr[2] += sum_ks partials (row block = 16 rows per block);
// optional h-step -> hTout. FP order identical to round 9.
// ---------------------------------------------------------------------------
__device__ __forceinline__ void reduce_body(
    const float* __restrict__ P, const ushort* __restrict__ Pb, int isbf,
    const float* __restrict__ Wn, const float* __restrict__ bn,
    ushort* __restrict__ hTout, int doH, float* xsr, float* xsl, float* Wl,
    int row0r, int tid) {
  const int col = tid & 31;
  if (doH)
    for (int i = tid; i < DIM * DIM; i += 256) Wl[i] = Wn[i];
#pragma unroll
  for (int rr = 0; rr < 2; ++rr) {
    const int lr = (tid >> 5) + rr * 8;
    const int row = row0r + lr;
    const int rbv = row >> 8, r255 = row & 255;
    const int w = r255 >> 6, rr6 = r255 & 63;
    const int rt = rr6 >> 4, q4 = (rr6 >> 2) & 3, i = rr6 & 3;
    const int ct = col >> 4, lane = q4 * 16 + (col & 15);
    const int base = ((rbv * 4 + w) * 8 + rt * 2 + ct) * 256 + lane * 4 + i;
    float s = xsr[rr];
    if (isbf) {
#pragma unroll
      for (int k = 0; k < KSPLIT; ++k)
        s += ubf(Pb[(size_t)k * (NATOMS * DIM) + base]);
    } else {
#pragma unroll
      for (int k = 0; k < KSPLIT; ++k)
        s += __builtin_nontemporal_load(&P[(size_t)k * (NATOMS * DIM) + base]);
    }
    xsr[rr] = s;
    if (doH) xsl[lr * DIM + col] = s;
  }
  if (doH) {
    __syncthreads();
    float wc[DIM];
#pragma unroll
    for (int d = 0; d < DIM; ++d) wc[d] = Wl[d * DIM + col];
    const float bb = bn[col];
#pragma unroll
    for (int rr = 0; rr < 2; ++rr) {
      const int lr = (tid >> 5) + rr * 8;
      float a = bb;
#pragma unroll
      for (int d = 0; d < DIM; ++d) a += xsl[lr * DIM + d] * wc[d];
      hTout[(size_t)col * NATOMS + row0r + lr] = bfr(fmaxf(a, 0.f));
    }
  }
}

// ---------------------------------------------------------------------------
// The persistent mega kernel: front | gemm1 | reduce | gemm2 | reduce |
// gemm3 | reduce, separated by grid barriers. 512 blocks, 2/CU resident.
// ---------------------------------------------------------------------------
__global__ __launch_bounds__(256, 2)
void cpi_mega(const int* __restrict__ fp, const float* __restrict__ adj,
              const int* __restrict__ words, const float* __restrict__ embfp,
              const float* __restrict__ embw, const float* __restrict__ Wg,
              const float* __restrict__ bg, float* __restrict__ out,
              float* __restrict__ P, ushort* __restrict__ Pb,
              ushort* __restrict__ Abf, ushort* __restrict__ hTa,
              ushort* __restrict__ hTb, int* __restrict__ bar) {
  __shared__ __align__(16) char smem[71680];  // 70 KB -> 2 blocks/CU
  float*  AbF = (float*)smem;           // gemm1: 2 x 32 KB fp32 A
  ushort* AbB = (ushort*)smem;          // gemm2: 3 x 16 KB bf16 A
  ushort* HbU = (ushort*)(smem + 65536);  // 3 x 2 KB h tiles
  float*  xsl = (float*)smem;           // reduce/front: 16 x 32 fp32
  float*  Wl  = (float*)(smem + 4096);  // 32 x 32 fp32

  const int tid   = threadIdx.x;
  const int bid   = blockIdx.x;
  const int wave  = tid >> 6;
  const int lane  = tid & 63;
  const int l15   = lane & 15;
  const int l4    = lane >> 4;
  const int rb    = bid & 31;
  const int ks    = bid >> 5;
  const int row0g = rb * BM;
  const int k0    = ks * KPB;
  const int row0r = bid * 16;
  const int col   = tid & 31;

  float xsr[2];  // this thread's 2 xs elements, live across all phases

  // ---------------- phase 0: front (words + gather + h0 -> hTa) ------------
  {
    const int wi = bid * 256 + tid;  // 512*256 = 131072 = NSEQ*DIM exactly
    out[NATOMS * DIM + wi] = embw[(size_t)words[wi >> 5] * DIM + (wi & 31)];
    for (int i = tid; i < DIM * DIM; i += 256) Wl[i] = Wg[i];
#pragma unroll
    for (int rr = 0; rr < 2; ++rr) {
      const int lr = (tid >> 5) + rr * 8;
      const float v = embfp[(size_t)fp[row0r + lr] * DIM + col];
      xsr[rr] = v;
      xsl[lr * DIM + col] = v;
    }
    __syncthreads();
    float wc[DIM];
#pragma unroll
    for (int d = 0; d < DIM; ++d) wc[d] = Wl[d * DIM + col];
    const float bb = bg[col];
#pragma unroll
    for (int rr = 0; rr < 2; ++rr) {
      const int lr = (tid >> 5) + rr * 8;
      float a = bb;
#pragma unroll
      for (int d = 0; d < DIM; ++d) a += xsl[lr * DIM + d] * wc[d];
      hTa[(size_t)col * NATOMS + row0r + lr] = bfr(fmaxf(a, 0.f));
    }
  }
  gridbar(bar, bar + 1, tid);

  // ---------------- phase 2: gemm1 (fp32 A -> bf16 MFMA + Abf image) -------
  {
    f32x4 acc[4][2];
#pragma unroll
    for (int rt = 0; rt < 4; ++rt)
#pragma unroll
      for (int ct = 0; ct < 2; ++ct) acc[rt][ct] = {0.f, 0.f, 0.f, 0.f};

    auto stage = [&](int buf, int t) {
      const int kb = k0 + t * BK;
#pragma unroll
      for (int i = 0; i < 8; ++i) {
        const int D = (wave * 8 + i) * 64 + lane;
        const int r = D >> 3;
        const int c = D & 7;
        const float* src =
            adj + (size_t)(row0g + r) * NATOMS + kb + ((c ^ (r & 7)) << 2);
        async16nt(AbF + buf * 8192 + (wave * 8 + i) * 256, src);
      }
      if (wave < 2) {
        const int E = wave * 64 + lane;
        const int n = E >> 2;
        const int s = E & 3;
        const ushort* src =
            hTa + (size_t)n * NATOMS + kb + (hslot(n, s) << 3);
        async16(HbU + buf * 1024 + wave * 512, src);
      }
    };

    stage(0, 0);
    asm volatile("s_waitcnt vmcnt(0)" ::: "memory");
    __syncthreads();

    int cur = 0;
#pragma unroll 1
    for (int t = 0; t < NT; ++t) {
      if (t + 1 < NT) stage(cur ^ 1, t + 1);

      const float*  Ac = AbF + cur * 8192;
      const ushort* Hc = HbU + cur * 1024;

      bf16x8 av[4];
#pragma unroll
      for (int rt = 0; rt < 4; ++rt) {
        const int r = wave * 64 + rt * 16 + l15;
        const float4 f0 =
            *(const float4*)(Ac + r * 32 + (((2 * l4) ^ (r & 7)) << 2));
        const float4 f1 =
            *(const float4*)(Ac + r * 32 + (((2 * l4 + 1) ^ (r & 7)) << 2));
        U8 u;
        u.u[0] = pkbf(f0.x, f0.y);
        u.u[1] = pkbf(f0.z, f0.w);
        u.u[2] = pkbf(f1.x, f1.y);
        u.u[3] = pkbf(f1.z, f1.w);
        av[rt] = u.v;
      }
      bf16x8 bv[2];
#pragma unroll
      for (int ct = 0; ct < 2; ++ct) {
        const int n = ct * 16 + l15;
        bv[ct] = *(const bf16x8*)(Hc + n * 32 + (hslot(n, l4) << 3));
      }

      ushort* Tb = Abf + (((size_t)ks * 32 + rb) * 16 + t) * (BM * BK);
#pragma unroll
      for (int rt = 0; rt < 4; ++rt) {
        const int r = wave * 64 + rt * 16 + l15;
        *(bf16x8*)(Tb + r * 32 + (aslot(r, l4) << 3)) = av[rt];
      }

#pragma unroll
      for (int rt = 0; rt < 4; ++rt)
#pragma unroll
        for (int ct = 0; ct < 2; ++ct)
          acc[rt][ct] = __builtin_amdgcn_mfma_f32_16x16x32_bf16(
              av[rt], bv[ct], acc[rt][ct], 0, 0, 0);

      asm volatile("s_waitcnt vmcnt(4)" ::: "memory");
      __syncthreads();
      cur ^= 1;
    }

    float* Pp = P + ((((size_t)ks * 32 + rb) * 4 + wave) * 8) * 256;
#pragma unroll
    for (int rt = 0; rt < 4; ++rt)
#pragma unroll
      for (int ct = 0; ct < 2; ++ct)
        *(f32x4*)(Pp + (rt * 2 + ct) * 256 + lane * 4) = acc[rt][ct];
  }
  gridbar(bar, bar + 1, tid);

  // ---------------- phase 4: reduce0 (fp32 P) + h1 -> hTb ------------------
  reduce_body(P, Pb, 0, Wg + DIM * DIM, bg + DIM, hTb, 1, xsr, xsl, Wl,
              row0r, tid);
  gridbar(bar, bar + 1, tid);

  // ---------------- phase 6: gemm2 layer 1 ---------------------------------
  gemm2_body(Abf, hTb, Pb, 0, AbB, HbU, tid, wave, lane, l15, l4, rb, ks, k0);
  gridbar(bar, bar + 1, tid);

  // ---------------- phase 8: reduce1 (bf16 Pb) + h2 -> hTa -----------------
  reduce_body(P, Pb, 1, Wg + 2 * DIM * DIM, bg + 2 * DIM, hTa, 1, xsr, xsl,
              Wl, row0r, tid);
  gridbar(bar, bar + 1, tid);

  // ---------------- phase 10: gemm3 (NT Abf reads) -------------------------
  gemm2_body(Abf, hTa, Pb, 1, AbB, HbU, tid, wave, lane, l15, l4, rb, ks, k0);
  gridbar(bar, bar + 1, tid);

  // ---------------- phase 12: reduce2 -> final xs --------------------------
  reduce_body(P, Pb, 1, Wg, bg, hTb, 0, xsr, xsl, Wl, row0r, tid);
#pragma unroll
  for (int rr = 0; rr < 2; ++rr) {
    const int lr = (tid >> 5) + rr * 8;
    out[(size_t)(row0r + lr) * DIM + col] = xsr[rr];
  }
}

extern "C" void kernel_launch(void* const* d_in, const int* in_sizes, int n_in,
                              void* d_out, int out_size, void* d_ws, size_t ws_size,
                              hipStream_t stream) {
  const int*   fp    = (const int*)d_in[0];
  const float* adj   = (const float*)d_in[1];
  const int*   words = (const int*)d_in[2];
  const float* embfp = (const float*)d_in[3];
  const float* embw  = (const float*)d_in[4];
  const float* Wg    = (const float*)d_in[5];
  const float* bg    = (const float*)d_in[6];

  float* out = (float*)d_out;

  float*  P   = (float*)d_ws;                               // 16 MB fp32 P0
  ushort* Pb  = (ushort*)P;                                 // 8 MB bf16 P1/P2
  ushort* Abf = (ushort*)(P + (size_t)KSPLIT * NATOMS * DIM);  // 128 MB bf16 A
  ushort* hTa = Abf + (size_t)NATOMS * NATOMS;              // 512 KB bf16 h^T
  ushort* hTb = hTa + (size_t)DIM * NATOMS;                 // 512 KB bf16 h^T
  int*    bar = (int*)(hTb + (size_t)DIM * NATOMS);         // {count, gen}

  hipMemsetAsync(bar, 0, 8, stream);  // count must start 0 each call
  cpi_mega<<<dim3(NBLK), dim3(256), 0, stream>>>(
      fp, adj, words, embfp, embw, Wg, bg, out, P, Pb, Abf, hTa, hTb, bar);
}

// Round 14
// 140.792 us; speedup vs baseline: 3.9064x; 2.9171x over previous
//
#include <hip/hip_runtime.h>
#include <hip/hip_bf16.h>
#include <cstdint>
#include <cstddef>

#define NATOMS 8192
#define DIM 32
#define NSEQ 4096
#define KSPLIT 16
#define BM 256
#define BK 32
#define KPB (NATOMS / KSPLIT)   // 512 k per block
#define NT (KPB / BK)           // 16 tiles

typedef __attribute__((address_space(1))) const void GV;
typedef __attribute__((address_space(3))) void LV;
using bf16x8 = __attribute__((ext_vector_type(8))) short;
using f32x4  = __attribute__((ext_vector_type(4))) float;
using u32x2  = __attribute__((ext_vector_type(2))) unsigned int;

__device__ __forceinline__ void async16(void* lds, const void* g) {
  __builtin_amdgcn_global_load_lds((GV*)g, (LV*)lds, 16, 0, 0);
}
// aux=2 -> NT: streaming, minimize cache retention (dead-after-read data).
__device__ __forceinline__ void async16nt(void* lds, const void* g) {
  __builtin_amdgcn_global_load_lds((GV*)g, (LV*)lds, 16, 0, 2);
}
__device__ __forceinline__ uint32_t pkbf(float lo, float hi) {
  union { __hip_bfloat16 b[2]; uint32_t u; } v;
  v.b[0] = __float2bfloat16(lo);
  v.b[1] = __float2bfloat16(hi);
  return v.u;
}
__device__ __forceinline__ float ubf(ushort u) {
  union { ushort u; __hip_bfloat16 b; } v;
  v.u = u;
  return __bfloat162float(v.b);
}
__device__ __forceinline__ ushort bfr(float a) {
  union { __hip_bfloat16 b; ushort u; } v;
  v.b = __float2bfloat16(a);
  return v.u;
}
union U8 { uint32_t u[4]; bf16x8 v; };

// bf16 tile image: per (ks,rb,t) tile of 256 rows x 32 k: row r = 64B = 4
// 16B slots; slot s holds k-chunk s ^ ((r>>1)&3).
__device__ __forceinline__ int aslot(int r, int g) { return g ^ ((r >> 1) & 3); }
__device__ __forceinline__ int hslot(int n, int g) { return g ^ ((n >> 1) & 3); }

// ---------------------------------------------------------------------------
// Layer-0 GEMM: P0(fp32) = A(fp32->bf16) @ hTa, MFMA; writes Abf tile image.
// BM=256, grid 512, 2 blocks/CU. Delivery-bound at the HBM mixed-stream floor.
// ---------------------------------------------------------------------------
__global__ __launch_bounds__(256, 2)
void cpi_gemm1(const float* __restrict__ A, const ushort* __restrict__ hT,
               float* __restrict__ P, ushort* __restrict__ Abf) {
  __shared__ float  Ab[2][BM * BK];   // 64 KiB, 8-slot XOR-swizzled fp32
  __shared__ ushort Hb[2][DIM * BK];  // 4 KiB, 4-slot XOR-swizzled bf16

  const int tid  = threadIdx.x;
  const int wave = tid >> 6;
  const int lane = tid & 63;
  const int l15  = lane & 15;
  const int l4   = lane >> 4;
  const int rb   = blockIdx.x & 31;
  const int ks   = blockIdx.x >> 5;
  const int row0 = rb * BM;
  const int k0   = ks * KPB;

  f32x4 acc[4][2];
#pragma unroll
  for (int rt = 0; rt < 4; ++rt)
#pragma unroll
    for (int ct = 0; ct < 2; ++ct) acc[rt][ct] = {0.f, 0.f, 0.f, 0.f};

  auto stage = [&](int buf, int t) {
    const int kb = k0 + t * BK;
#pragma unroll
    for (int i = 0; i < 8; ++i) {
      const int D = (wave * 8 + i) * 64 + lane;  // fp32 16B chunk 0..2047
      const int r = D >> 3;
      const int c = D & 7;
      const float* src =
          A + (size_t)(row0 + r) * NATOMS + kb + ((c ^ (r & 7)) << 2);
      async16nt(&Ab[buf][(wave * 8 + i) * 256], src);  // NT: dead after read
    }
    if (wave < 2) {  // h tile: 2KB = 128 chunks
      const int E = wave * 64 + lane;
      const int n = E >> 2;
      const int s = E & 3;
      const ushort* src = hT + (size_t)n * NATOMS + kb + (hslot(n, s) << 3);
      async16(&Hb[buf][wave * 512], src);
    }
  };

  stage(0, 0);
  asm volatile("s_waitcnt vmcnt(0)" ::: "memory");
  __syncthreads();

  int cur = 0;
#pragma unroll 1
  for (int t = 0; t < NT; ++t) {
    if (t + 1 < NT) stage(cur ^ 1, t + 1);

    const float*  Ac = &Ab[cur][0];
    const ushort* Hc = &Hb[cur][0];

    // A fragments: convert fp32 LDS -> bf16
    bf16x8 av[4];
#pragma unroll
    for (int rt = 0; rt < 4; ++rt) {
      const int r = wave * 64 + rt * 16 + l15;
      const float4 f0 =
          *(const float4*)(Ac + r * 32 + (((2 * l4) ^ (r & 7)) << 2));
      const float4 f1 =
          *(const float4*)(Ac + r * 32 + (((2 * l4 + 1) ^ (r & 7)) << 2));
      U8 u;
      u.u[0] = pkbf(f0.x, f0.y);
      u.u[1] = pkbf(f0.z, f0.w);
      u.u[2] = pkbf(f1.x, f1.y);
      u.u[3] = pkbf(f1.z, f1.w);
      av[rt] = u.v;
    }
    bf16x8 bv[2];
#pragma unroll
    for (int ct = 0; ct < 2; ++ct) {
      const int n = ct * 16 + l15;
      bv[ct] = *(const bf16x8*)(Hc + n * 32 + (hslot(n, l4) << 3));
    }

    // store bf16 tile image (each wave instruction = contiguous 1KB)
    ushort* Tb = Abf + (((size_t)ks * 32 + rb) * 16 + t) * (BM * BK);
#pragma unroll
    for (int rt = 0; rt < 4; ++rt) {
      const int r = wave * 64 + rt * 16 + l15;
      *(bf16x8*)(Tb + r * 32 + (aslot(r, l4) << 3)) = av[rt];
    }

#pragma unroll
    for (int rt = 0; rt < 4; ++rt)
#pragma unroll
      for (int ct = 0; ct < 2; ++ct)
        acc[rt][ct] = __builtin_amdgcn_mfma_f32_16x16x32_bf16(
            av[rt], bv[ct], acc[rt][ct], 0, 0, 0);

    // vmcnt(4): the 4 image stores are the newest FIFO entries; depth-4 wait
    // retires all staging loads without stalling on store acks.
    asm volatile("s_waitcnt vmcnt(4)" ::: "memory");
    __syncthreads();
    cur ^= 1;
  }

  float* Pp = P + ((((size_t)ks * 32 + rb) * 4 + wave) * 8) * 256;
#pragma unroll
  for (int rt = 0; rt < 4; ++rt)
#pragma unroll
    for (int ct = 0; ct < 2; ++ct)
      *(f32x4*)(Pp + (rt * 2 + ct) * 256 + lane * 4) = acc[rt][ct];
}

// ---------------------------------------------------------------------------
// Layers 1/2 GEMM: Pb(bf16) = Abf(bf16 tile image) @ hT, MFMA.
// 3-deep LDS pipeline, counted per-wave vmcnt (never 0 in steady state).
// ---------------------------------------------------------------------------
__global__ __launch_bounds__(256, 2)
void cpi_gemm2(const ushort* __restrict__ Abf, const ushort* __restrict__ hT,
               ushort* __restrict__ Pb, const int ntA) {
  __shared__ ushort Ab[3][BM * BK];   // 3 x 16 KiB (bf16)
  __shared__ ushort Hb[3][DIM * BK];  // 3 x 2 KiB

  const int tid  = threadIdx.x;
  const int wave = tid >> 6;
  const int lane = tid & 63;
  const int l15  = lane & 15;
  const int l4   = lane >> 4;
  const int rb   = blockIdx.x & 31;
  const int ks   = blockIdx.x >> 5;
  const int k0   = ks * KPB;

  f32x4 acc[4][2];
#pragma unroll
  for (int rt = 0; rt < 4; ++rt)
#pragma unroll
    for (int ct = 0; ct < 2; ++ct) acc[rt][ct] = {0.f, 0.f, 0.f, 0.f};

  auto stage = [&](int buf, int t) {
    const ushort* Tb = Abf + (((size_t)ks * 32 + rb) * 16 + t) * (BM * BK);
#pragma unroll
    for (int i = 0; i < 4; ++i) {  // 16KB linear copy
      const ushort* src = Tb + ((wave * 4 + i) * 64 + lane) * 8;
      void* dst = &Ab[buf][(wave * 4 + i) * 512];
      if (ntA)
        async16nt(dst, src);  // layer 2: Abf dead after this read
      else
        async16(dst, src);
    }
    if (wave < 2) {
      const int kb = k0 + t * BK;
      const int E = wave * 64 + lane;
      const int n = E >> 2;
      const int s = E & 3;
      const ushort* src = hT + (size_t)n * NATOMS + kb + (hslot(n, s) << 3);
      async16(&Hb[buf][wave * 512], src);
    }
  };

  stage(0, 0);
  stage(1, 1);

#pragma unroll 1
  for (int t = 0; t < NT; ++t) {
    // own stage-t loads landed (stage t+1 may stay in flight)
    if (t + 1 < NT) {
      if (wave < 2)
        asm volatile("s_waitcnt vmcnt(5)" ::: "memory");
      else
        asm volatile("s_waitcnt vmcnt(4)" ::: "memory");
    } else {
      asm volatile("s_waitcnt vmcnt(0)" ::: "memory");
    }
    __syncthreads();  // everyone's tile-t LDS writes visible; buf(t+2)%3 free
    if (t + 2 < NT) stage((t + 2) % 3, t + 2);

    const ushort* Ac = &Ab[t % 3][0];
    const ushort* Hc = &Hb[t % 3][0];

    bf16x8 av[4], bv[2];
#pragma unroll
    for (int rt = 0; rt < 4; ++rt) {
      const int r = wave * 64 + rt * 16 + l15;
      av[rt] = *(const bf16x8*)(Ac + r * 32 + (aslot(r, l4) << 3));
    }
#pragma unroll
    for (int ct = 0; ct < 2; ++ct) {
      const int n = ct * 16 + l15;
      bv[ct] = *(const bf16x8*)(Hc + n * 32 + (hslot(n, l4) << 3));
    }

#pragma unroll
    for (int rt = 0; rt < 4; ++rt)
#pragma unroll
      for (int ct = 0; ct < 2; ++ct)
        acc[rt][ct] = __builtin_amdgcn_mfma_f32_16x16x32_bf16(
            av[rt], bv[ct], acc[rt][ct], 0, 0, 0);
  }

  // bf16 partials: pack 4 fp32 -> 2 dwords; 8B/lane/frag, coalesced 512B/wave
  ushort* Pp = Pb + ((((size_t)ks * 32 + rb) * 4 + wave) * 8) * 256;
#pragma unroll
  for (int rt = 0; rt < 4; ++rt)
#pragma unroll
    for (int ct = 0; ct < 2; ++ct) {
      u32x2 u;
      u.x = pkbf(acc[rt][ct].x, acc[rt][ct].y);
      u.y = pkbf(acc[rt][ct].z, acc[rt][ct].w);
      *(u32x2*)(Pp + (rt * 2 + ct) * 256 + lane * 4) = u;
    }
}

// ---------------------------------------------------------------------------
// Front kernel: blocks [0,1024): xs = emb_fp[fp] -> out, hT = bf16(relu(
// xs@W0+b0)); blocks [1024,1536): word_vectors = emb_word[words].
// ---------------------------------------------------------------------------
__global__ __launch_bounds__(256)
void cpi_front(const int* __restrict__ fp, const float* __restrict__ embfp,
               const float* __restrict__ W, const float* __restrict__ b,
               float* __restrict__ xs, ushort* __restrict__ hT,
               const int* __restrict__ words, const float* __restrict__ embw,
               float* __restrict__ wout) {
  if (blockIdx.x >= NATOMS / 8) {  // words part (block-uniform branch)
    const int i = (blockIdx.x - NATOMS / 8) * 256 + threadIdx.x;
    wout[i] = embw[(size_t)words[i >> 5] * DIM + (i & 31)];
    return;
  }
  __shared__ float xsl[8][DIM];
  __shared__ float Wl[DIM][DIM];
  const int tid = threadIdx.x;
  const int col = tid & 31;
  const int r8  = tid >> 5;
  const int row = blockIdx.x * 8 + r8;
  const int f   = fp[row];
  const float v = embfp[(size_t)f * DIM + col];
  xs[(size_t)row * DIM + col] = v;
  xsl[r8][col] = v;
#pragma unroll
  for (int i = 0; i < 4; ++i) {
    const int idx = tid + i * 256;
    ((float*)Wl)[idx] = W[idx];
  }
  __syncthreads();
  float a = b[col];
#pragma unroll
  for (int d = 0; d < DIM; ++d) a += xsl[r8][d] * Wl[d][col];
  hT[(size_t)col * NATOMS + row] = bfr(fmaxf(a, 0.f));
}

// ---------------------------------------------------------------------------
// xs += sum_ks P[ks] (fragment-native BM=256 layout; fp32 or bf16 partials);
// optionally hT[col][row] = bf16(relu(xs@W + b)) for the next layer
// ---------------------------------------------------------------------------
__global__ __launch_bounds__(256)
void cpi_reduce_h(const float* __restrict__ P, const ushort* __restrict__ Pb,
                  const int p_is_bf16, const float* __restrict__ W,
                  const float* __restrict__ b, float* __restrict__ xs,
                  ushort* __restrict__ hT, const int compute_h) {
  __shared__ float xsl[8][DIM];
  __shared__ float Wl[DIM][DIM];
  const int tid = threadIdx.x;
  const int col = tid & 31;
  const int r8  = tid >> 5;
  const int row = blockIdx.x * 8 + r8;
  const size_t off = (size_t)row * DIM + col;
  float s = xs[off];
  {
    // inverse of the BM=256 fragment store
    const int rbv = row >> 8, rr = row & 255;
    const int w = rr >> 6, rr6 = rr & 63;
    const int rt = rr6 >> 4, q4 = (rr6 >> 2) & 3, i = rr6 & 3;
    const int ct = col >> 4, lane = q4 * 16 + (col & 15);
    const int base = ((rbv * 4 + w) * 8 + rt * 2 + ct) * 256 + lane * 4 + i;
    if (p_is_bf16) {  // uniform branch
#pragma unroll
      for (int k = 0; k < KSPLIT; ++k)
        s += ubf(Pb[(size_t)k * (NATOMS * DIM) + base]);
    } else {
#pragma unroll
      for (int k = 0; k < KSPLIT; ++k)
        s += __builtin_nontemporal_load(&P[(size_t)k * (NATOMS * DIM) + base]);
    }
  }
  xs[off] = s;
  if (compute_h) {  // uniform branch
    xsl[r8][col] = s;
#pragma unroll
    for (int i = 0; i < 4; ++i) {
      const int idx = tid + i * 256;
      ((float*)Wl)[idx] = W[idx];
    }
    __syncthreads();
    float a = b[col];
#pragma unroll
    for (int d = 0; d < DIM; ++d) a += xsl[r8][d] * Wl[d][col];
    hT[(size_t)col * NATOMS + row] = bfr(fmaxf(a, 0.f));
  }
}

extern "C" void kernel_launch(void* const* d_in, const int* in_sizes, int n_in,
                              void* d_out, int out_size, void* d_ws, size_t ws_size,
                              hipStream_t stream) {
  const int*   fp    = (const int*)d_in[0];
  const float* adj   = (const float*)d_in[1];
  const int*   words = (const int*)d_in[2];
  const float* embfp = (const float*)d_in[3];
  const float* embw  = (const float*)d_in[4];
  const float* Wg    = (const float*)d_in[5];
  const float* bg    = (const float*)d_in[6];

  float* out = (float*)d_out;
  float* xs  = out;                 // [8192*32] final compound_vector
  float* wv  = out + NATOMS * DIM;  // [4096*32] word vectors

  float*  P   = (float*)d_ws;                               // 16 MB fp32 P0
  ushort* Pb  = (ushort*)P;                                 // 8 MB bf16 P1/P2
  ushort* Abf = (ushort*)(P + (size_t)KSPLIT * NATOMS * DIM);  // 128 MB bf16 A
  ushort* hTa = Abf + (size_t)NATOMS * NATOMS;              // 512 KB bf16 h^T
  ushort* hTb = hTa + (size_t)DIM * NATOMS;                 // 512 KB bf16 h^T

  cpi_front<<<dim3(NATOMS / 8 + NSEQ * DIM / 256), dim3(256), 0, stream>>>(
      fp, embfp, Wg, bg, xs, hTa, words, embw, wv);

  // layer 0: fp32 A staged (NT), bf16 MFMA, emits Abf tile image, fp32 P
  cpi_gemm1<<<dim3(512), dim3(256), 0, stream>>>(adj, hTa, P, Abf);
  cpi_reduce_h<<<dim3(NATOMS / 8), dim3(256), 0, stream>>>(
      P, Pb, 0, Wg + DIM * DIM, bg + DIM, xs, hTb, 1);

  // layer 1: bf16 tile-image MFMA (Abf hot in Infinity Cache), bf16 P
  cpi_gemm2<<<dim3(512), dim3(256), 0, stream>>>(Abf, hTb, Pb, 0);
  cpi_reduce_h<<<dim3(NATOMS / 8), dim3(256), 0, stream>>>(
      P, Pb, 1, Wg + 2 * DIM * DIM, bg + 2 * DIM, xs, hTa, 1);

  // layer 2: bf16 tile-image MFMA, NT A reads (Abf dead after), bf16 P
  cpi_gemm2<<<dim3(512), dim3(256), 0, stream>>>(Abf, hTa, Pb, 1);
  cpi_reduce_h<<<dim3(NATOMS / 8), dim3(256), 0, stream>>>(
      P, Pb, 1, Wg, bg, xs, hTb, 0);
}